// Round 11
// baseline (249.371 us; speedup 1.0000x reference)
//
#include <hip/hip_runtime.h>
#include <hip/hip_bf16.h>
#include <stdint.h>

#define DD 2048
#define SS 16384
#define HH 250
#define GEMMB_GRID 264

typedef __attribute__((ext_vector_type(8))) short bf16x8;
typedef __attribute__((ext_vector_type(4))) short bf16x4;
typedef __attribute__((ext_vector_type(4))) float f32x4;

__device__ __forceinline__ unsigned short f2bf(float f){
  union { float f; uint32_t u; } v; v.f = f;
  uint32_t u = v.u;
  return (unsigned short)((u + 0x7fffu + ((u >> 16) & 1u)) >> 16);
}
__device__ __forceinline__ float bf2f(unsigned short h){
  union { uint32_t u; float f; } v; v.u = ((uint32_t)h) << 16; return v.f;
}
__device__ __forceinline__ bf16x4 pk4(float4 a){
  bf16x4 v;
  v[0]=(short)f2bf(a.x); v[1]=(short)f2bf(a.y); v[2]=(short)f2bf(a.z); v[3]=(short)f2bf(a.w);
  return v;
}
__device__ __forceinline__ bf16x8 pk8(float4 a, float4 c, bool alive){
  bf16x8 v;
  v[0]=(short)f2bf(a.x); v[1]=(short)f2bf(a.y); v[2]=(short)f2bf(a.z); v[3]=(short)f2bf(a.w);
  v[4]=(short)f2bf(c.x); v[5]=(short)f2bf(c.y); v[6]=(short)f2bf(c.z); v[7]=(short)f2bf(c.w);
  if(!alive){
    #pragma unroll
    for(int i = 0; i < 8; i++) v[i] = 0;
  }
  return v;
}
__device__ __forceinline__ float fast_tanh(float x){
  return 1.0f - 2.0f / (1.0f + __expf(2.0f * x));
}
__device__ __forceinline__ void gl_lds16(const void* g, void* l){
  __builtin_amdgcn_global_load_lds((const __attribute__((address_space(1))) void*)g,
                                   (__attribute__((address_space(3))) void*)l, 16, 0, 0);
}

// ---------- ballot scan: 1 block, 1024 threads, 16 coalesced rounds ----------
__global__ __launch_bounds__(1024) void scan_kernel(const int* __restrict__ mask,
                                                    int* __restrict__ idx,
                                                    int* __restrict__ cpos,
                                                    int* __restrict__ mcount)
{
  __shared__ int wsum[16];
  const int t = threadIdx.x, lane = t & 63, w = t >> 6;
  int running = 0;
  for(int k = 0; k < 16; k++){
    const int e = k * 1024 + t;
    const int m = (mask[e] == 0);
    unsigned long long bal = __ballot(m);
    if(lane == 0) wsum[w] = __popcll(bal);
    __syncthreads();
    int wpre = 0;
    for(int i = 0; i < w; i++) wpre += wsum[i];
    int tot = wpre;
    for(int i = w; i < 16; i++) tot += wsum[i];
    const int lpre = __popcll(bal & ((1ull << lane) - 1ull));
    const int pos = running + wpre + lpre;
    if(m){ idx[pos] = e; cpos[e] = pos; } else cpos[e] = -1;
    running += tot;
    __syncthreads();
  }
  if(t == 0){
    mcount[0] = running;
    mcount[1] = (running + 255) & ~255;   // gemmA 256-row tile pad
    mcount[2] = (running + 63) & ~63;     // gemmB 64-row tile pad
  }
}

// ---------- mega: W_ctx conv | W_p1a conv | matvecs (no enc convert!) ----------
// roles: [0,256) W_ctx | [256,288) W_p1a | [288,1312) matvec
__global__ __launch_bounds__(256) void mega_kernel(
    const float* __restrict__ W_ctx, unsigned short* __restrict__ wctxb,
    const float* __restrict__ W_p1, unsigned short* __restrict__ wp1ab,
    const float* __restrict__ s_prev, const float* __restrict__ cmr,
    const float* __restrict__ Wq, const float* __restrict__ bq,
    const float* __restrict__ Winfo,
    float* __restrict__ twq, float* __restrict__ tdh)
{
  const int b = blockIdx.x, t = threadIdx.x;
  if(b < 256){                                   // W_ctx: 1,048,576 float4 chunks
    const float4* in4 = (const float4*)W_ctx;
    bf16x4* out4 = (bf16x4*)wctxb;
    const int gt = b * 256 + t;                  // 65536 threads
    for(int i = gt; i < 1048576; i += 65536) out4[i] = pk4(in4[i]);
  } else if(b < 288){                            // W_p1a: 131,072 bf16x4 chunks
    bf16x4* out4 = (bf16x4*)wp1ab;
    const int gt = (b - 256) * 256 + t;          // 8192 threads
    #pragma unroll
    for(int k = 0; k < 16; k++){
      int i = gt + k * 8192;
      int row = i >> 9, col = i & 511;
      bf16x4 v;
      if(row < HH){
        v = pk4(*(const float4*)(W_p1 + (size_t)row * (3 * DD) + (col << 2)));
      } else {
        v[0] = 0; v[1] = 0; v[2] = 0; v[3] = 0;
      }
      out4[i] = v;
    }
  } else {                                       // twq / tdh matvecs
    int vb = b - 288;
    int wid = t >> 6, lane = t & 63;
    bool isq = vb < 512;
    int r = (isq ? vb : vb - 512) * 4 + wid;
    const float* M = (isq ? Wq : Winfo) + (size_t)r * DD;
    const float* x = isq ? s_prev : cmr;
    float s = 0.f;
    for(int i = lane; i < DD; i += 64) s += M[i] * x[i];
    #pragma unroll
    for(int o = 32; o; o >>= 1) s += __shfl_xor(s, o);
    if(lane == 0){
      if(isq) twq[r] = fast_tanh(s + bq[r]);
      else    tdh[r] = fast_tanh(s);
    }
  }
}

// ---------- gemmA B-staging helper (linear LDS dest + pre-swizzled source) ----------
__device__ __forceinline__ void stage_half(const unsigned short* __restrict__ g,
                                           int grow0, int kt, char* ldsbase,
                                           int wid, int lane)
{
  const int srow = lane >> 3;
  const int c = (lane & 7) ^ srow;
  #pragma unroll
  for(int i = 0; i < 2; i++){
    int r8 = (wid * 2 + i) * 8;
    gl_lds16(g + (size_t)(grow0 + r8 + srow) * DD + kt + c * 8,
             ldsbase + r8 * 128);
  }
}
#define RDF(base, lr, kc) (*(const bf16x8*)((base) + (lr) * 128 + (((kc) * 16) ^ (((lr) & 7) << 4))))

// ---------- gemmA: tanh(enc[idx] @ W_ctx^T), reg-staged f32 A-gather + cvt,
//            BM=BN=256 BK=64, 4-phase, XCD-grouped, + bias2 tail ----------
__global__ __launch_bounds__(512, 2) void gemmA_kernel(
    const float* __restrict__ enc, const int* __restrict__ idx,
    const unsigned short* __restrict__ B, const int* __restrict__ mcount,
    unsigned short* __restrict__ Ct,
    const float* __restrict__ wp1, const float* __restrict__ bp1,
    const float* __restrict__ twq, const float* __restrict__ tdh,
    float* __restrict__ bias2)
{
  const int tid = threadIdx.x, lane = tid & 63, wid = tid >> 6;
  if(blockIdx.x >= 512){               // bias2 tail: 32 blocks x 8 waves
    int h = (blockIdx.x - 512) * 8 + wid;
    if(h >= HH){ if(lane == 0 && h < 256) bias2[h] = 0.f; return; }
    const float* r1 = wp1 + (size_t)h * (3 * DD) + DD;
    const float* r2 = wp1 + (size_t)h * (3 * DD) + 2 * DD;
    float s = 0.f;
    for(int i = lane; i < DD; i += 64) s += r1[i] * twq[i] + r2[i] * tdh[i];
    #pragma unroll
    for(int o = 32; o; o >>= 1) s += __shfl_xor(s, o);
    if(lane == 0) bias2[h] = s + bp1[h];
    return;
  }
  __shared__ alignas(128) char lds[131072];   // A 32K x2 | B 32K x2
  const int wm = wid >> 2, wn = wid & 3;          // 2M x 4N waves
  // XCD grouping: all 8 n-siblings of m-tile mt land on one XCD (bid%8 const)
  const int slot = blockIdx.x >> 3;
  const int mt = (blockIdx.x & 7) + ((slot >> 3) << 3);
  const int n0 = (slot & 7) * 256;
  const int MT = mcount[1] >> 8;
  if(mt >= MT) return;
  const int m0 = mt * 256;
  const int frow = lane & 15, kch = lane >> 4;

  // A reg-staging: thread handles row r_loc, col-half p (32 f32 = 128B per K-step)
  const int p = lane & 1;
  const int r_loc = wid * 32 + (lane >> 1);
  const int mc0 = mcount[0];
  const bool alive = (m0 + r_loc) < mc0;
  const int ridx = alive ? idx[m0 + r_loc] : idx[0];
  const float* rp = enc + (size_t)ridx * DD + p * 32;
  int wroff[4];
  #pragma unroll
  for(int j = 0; j < 4; j++)
    wroff[j] = r_loc * 128 + (((p * 4 + j) * 16) ^ ((r_loc & 7) << 4));

  f32x4 acc[8][4] = {};
  float4 ld[8];

  // prologue: A(0) loads; B(0), B(1) stages; cvt+write A(0) (implicit vmcnt
  // wait retires A-loads & everything older); lgkm drain; vmcnt(4) -> B(0)
  // resident, B(1) may stay in flight.
  #pragma unroll
  for(int j = 0; j < 8; j++) ld[j] = *(const float4*)(rp + j * 4);
  stage_half(B, n0,        0, lds + 65536,         wid, lane);
  stage_half(B, n0 + 128,  0, lds + 65536 + 16384, wid, lane);
  stage_half(B, n0,       64, lds + 98304,         wid, lane);
  stage_half(B, n0 + 128, 64, lds + 98304 + 16384, wid, lane);
  #pragma unroll
  for(int j = 0; j < 4; j++)
    *(bf16x8*)(lds + wroff[j]) = pk8(ld[2 * j], ld[2 * j + 1], alive);
  asm volatile("s_waitcnt lgkmcnt(0)" ::: "memory");
  asm volatile("s_waitcnt vmcnt(4)" ::: "memory");
  __builtin_amdgcn_s_barrier();

  #pragma unroll 2
  for(int t = 0; t < 32; t++){
    const int d = t & 1;
    char* Ab = lds + d * 32768;
    char* An = lds + (d ^ 1) * 32768;
    char* Bb = lds + 65536 + d * 32768;
    bf16x8 bfr[4][2];
    #pragma unroll
    for(int q = 0; q < 4; q++){
      if(q == 0){
        #pragma unroll
        for(int nr = 0; nr < 4; nr++){
          int row = wn * 64 + nr * 16 + frow;
          #pragma unroll
          for(int ks = 0; ks < 2; ks++) bfr[nr][ks] = RDF(Bb, row, ks * 4 + kch);
        }
      }
      bf16x8 afr[2][2];
      #pragma unroll
      for(int mi = 0; mi < 2; mi++){
        int row = wm * 128 + (q * 2 + mi) * 16 + frow;
        #pragma unroll
        for(int ks = 0; ks < 2; ks++) afr[mi][ks] = RDF(Ab, row, ks * 4 + kch);
      }
      // staging issues
      if(q == 0){
        if(t + 1 < 32){
          #pragma unroll
          for(int j = 0; j < 8; j++) ld[j] = *(const float4*)(rp + (t + 1) * 64 + j * 4);
        }
      } else if(q == 1){
        if(t + 2 < 32) stage_half(B, n0,       (t + 2) * 64, Bb,         wid, lane);
      } else if(q == 2){
        if(t + 2 < 32) stage_half(B, n0 + 128, (t + 2) * 64, Bb + 16384, wid, lane);
      }
      __builtin_amdgcn_s_barrier();
      __builtin_amdgcn_sched_barrier(0);
      __builtin_amdgcn_s_setprio(1);
      #pragma unroll
      for(int mi = 0; mi < 2; mi++)
        #pragma unroll
        for(int nr = 0; nr < 4; nr++)
          #pragma unroll
          for(int ks = 0; ks < 2; ks++)
            acc[q * 2 + mi][nr] = __builtin_amdgcn_mfma_f32_16x16x32_bf16(
                afr[mi][ks], bfr[nr][ks], acc[q * 2 + mi][nr], 0, 0, 0);
      __builtin_amdgcn_s_setprio(0);
      __builtin_amdgcn_sched_barrier(0);
      if(q == 3){
        // cvt forces the compiler's exact vmcnt wait for the A-regs, which
        // also retires all OLDER vm ops (incl. B(t+1) staged last tile).
        if(t + 1 < 32){
          #pragma unroll
          for(int j = 0; j < 4; j++)
            *(bf16x8*)(An + wroff[j]) = pk8(ld[2 * j], ld[2 * j + 1], alive);
        }
        asm volatile("s_waitcnt lgkmcnt(0)" ::: "memory");
        asm volatile("s_waitcnt vmcnt(4)" ::: "memory");  // B(t+2) may stay in flight
      }
      __builtin_amdgcn_s_barrier();
    }
  }

  // epilogue: fused tanh + bf16 store (r innermost -- R3-verified clean WRITE)
  const int r0 = m0 + wm * 128 + (lane >> 4) * 4;
  const int c0 = n0 + wn * 64 + frow;
  #pragma unroll
  for(int mr = 0; mr < 8; mr++)
    #pragma unroll
    for(int nr = 0; nr < 4; nr++)
      #pragma unroll
      for(int r = 0; r < 4; r++)
        Ct[(size_t)(r0 + mr * 16 + r) * DD + c0 + nr * 16] = f2bf(fast_tanh(acc[mr][nr][r]));
}

// ---------- gemmB: e = exp(W_p2 . relu(tanh @ W_p1a^T + bias2) + b_p2) ----------
__global__ __launch_bounds__(512, 4) void gemmB_kernel(
    const unsigned short* __restrict__ A, const unsigned short* __restrict__ B,
    const int* __restrict__ mcount, const float* __restrict__ bias2,
    const float* __restrict__ w2, const float* __restrict__ bp2,
    float* __restrict__ attnc, float* __restrict__ Tpart)
{
  __shared__ alignas(128) char lds[81920];    // A 8K x2 | B 32K x2
  __shared__ float sred[8][32];
  const int tid = threadIdx.x, lane = tid & 63, wid = tid >> 6;
  const int wm = wid >> 2, wn = wid & 3;
  const int m0 = blockIdx.x * 64;
  const int mc0 = mcount[0], mc2 = mcount[2];
  if(m0 >= mc2){ if(tid == 0) Tpart[blockIdx.x] = 0.f; return; }
  const int frow = lane & 15, kch = lane >> 4;
  const int srow = lane >> 3, sc = ((lane & 7) ^ srow) * 8;

  f32x4 acc[2][4] = {};

  gl_lds16(A + (size_t)(m0 + wid * 8 + srow) * DD + sc, lds + wid * 1024);
  #pragma unroll
  for(int i = 0; i < 4; i++){
    int l = wid + 8 * i;
    gl_lds16(B + (size_t)(l * 8 + srow) * DD + sc,      lds + 16384 + l * 1024);
    gl_lds16(B + (size_t)(l * 8 + srow) * DD + 64 + sc, lds + 49152 + l * 1024);
  }
  asm volatile("s_waitcnt vmcnt(4)" ::: "memory");
  __builtin_amdgcn_s_barrier();

  #pragma unroll 2
  for(int t = 0; t < 32; t++){
    const int d = t & 1;
    char* Ab = lds + d * 8192;
    char* An = lds + (d ^ 1) * 8192;
    char* Bb = lds + 16384 + d * 32768;
    bf16x8 bfr[4][2], afr[2];
    #pragma unroll
    for(int q = 0; q < 2; q++){
      if(q == 0){
        #pragma unroll
        for(int nr = 0; nr < 4; nr++){
          int row = wn * 64 + nr * 16 + frow;
          #pragma unroll
          for(int ks = 0; ks < 2; ks++) bfr[nr][ks] = RDF(Bb, row, ks * 4 + kch);
        }
      }
      {
        int row = wm * 32 + q * 16 + frow;
        #pragma unroll
        for(int ks = 0; ks < 2; ks++) afr[ks] = RDF(Ab, row, ks * 4 + kch);
      }
      if(q == 0){
        if(t + 1 < 32)
          gl_lds16(A + (size_t)(m0 + wid * 8 + srow) * DD + (t + 1) * 64 + sc, An + wid * 1024);
      } else {
        if(t + 2 < 32){
          #pragma unroll
          for(int i = 0; i < 4; i++){
            int l = wid + 8 * i;
            gl_lds16(B + (size_t)(l * 8 + srow) * DD + (t + 2) * 64 + sc, Bb + l * 1024);
          }
        }
      }
      __builtin_amdgcn_s_barrier();
      __builtin_amdgcn_sched_barrier(0);
      __builtin_amdgcn_s_setprio(1);
      #pragma unroll
      for(int nr = 0; nr < 4; nr++)
        #pragma unroll
        for(int ks = 0; ks < 2; ks++)
          acc[q][nr] = __builtin_amdgcn_mfma_f32_16x16x32_bf16(afr[ks], bfr[nr][ks], acc[q][nr], 0, 0, 0);
      __builtin_amdgcn_s_setprio(0);
      __builtin_amdgcn_sched_barrier(0);
      if(q == 1){
        if(t < 30)       asm volatile("s_waitcnt vmcnt(4)" ::: "memory");
        else if(t == 30) asm volatile("s_waitcnt vmcnt(0)" ::: "memory");
      }
      __builtin_amdgcn_s_barrier();
    }
  }

  float w2v[4], b2v[4];
  #pragma unroll
  for(int in = 0; in < 4; in++){
    int n = wn * 64 + in * 16 + frow;
    w2v[in] = (n < HH) ? w2[n] : 0.f;
    b2v[in] = bias2[n];
  }
  #pragma unroll
  for(int mi = 0; mi < 2; mi++){
    #pragma unroll
    for(int r = 0; r < 4; r++){
      float s = 0.f;
      #pragma unroll
      for(int in = 0; in < 4; in++){
        float h = acc[mi][in][r] + b2v[in];
        s += (h > 0.f ? h : 0.f) * w2v[in];
      }
      s += __shfl_xor(s, 1); s += __shfl_xor(s, 2);
      s += __shfl_xor(s, 4); s += __shfl_xor(s, 8);
      if(frow == 0) sred[wid][mi * 16 + (lane >> 4) * 4 + r] = s;
    }
  }
  __syncthreads();
  if(tid < 64){
    int wmr = tid >> 5, rr = tid & 31;
    float s = sred[wmr * 4][rr] + sred[wmr * 4 + 1][rr] + sred[wmr * 4 + 2][rr]
            + sred[wmr * 4 + 3][rr] + bp2[0];
    int j = m0 + tid;
    float e = (j < mc0) ? __expf(s) : 0.f;
    if(j < mc0) attnc[j] = e;
    #pragma unroll
    for(int o = 32; o; o >>= 1) e += __shfl_xor(e, o);
    if(tid == 0) Tpart[blockIdx.x] = e;
  }
}

// ---------- norm+scatter (blocks 0..63) | ctx partials from enc f32 (64..319) ----------
__global__ __launch_bounds__(256) void normctx_kernel(
    const float* __restrict__ attnc, const int* __restrict__ cpos,
    const int* __restrict__ idx, const int* __restrict__ mcount,
    const float* __restrict__ Tpart, const float* __restrict__ enc,
    float* __restrict__ out, float* __restrict__ part)
{
  const int b = blockIdx.x, t = threadIdx.x;
  if(b < 64){
    __shared__ float sT;
    if(t == 0){
      float s = 0.f;
      for(int i = 0; i < GEMMB_GRID; i++) s += Tpart[i];
      sT = 1.0f / s;
    }
    __syncthreads();
    int i = b * 256 + t;
    int cp = cpos[i];
    out[i] = (cp >= 0) ? attnc[cp] * sT : 0.f;
  } else {
    const int bb = b - 64;
    const int mc0 = mcount[0];
    const int chunk = (mc0 + 255) >> 8;
    const int j0 = bb * chunk;
    const int j1 = min(j0 + chunk, mc0);
    float a[8] = {};
    for(int j = j0; j < j1; j++){
      float e = attnc[j];
      const float4* p4 = (const float4*)(enc + (size_t)idx[j] * DD + t * 8);
      float4 x = p4[0], y = p4[1];
      a[0] += e * x.x; a[1] += e * x.y; a[2] += e * x.z; a[3] += e * x.w;
      a[4] += e * y.x; a[5] += e * y.y; a[6] += e * y.z; a[7] += e * y.w;
    }
    float* o = part + (size_t)bb * DD + t * 8;
    #pragma unroll
    for(int k = 0; k < 8; k++) o[k] = a[k];
  }
}

__global__ __launch_bounds__(256) void ctxr_kernel(
    const float* __restrict__ part, const float* __restrict__ Tpart,
    float* __restrict__ out)
{
  __shared__ float sT;
  if(threadIdx.x == 0){
    float s = 0.f;
    for(int i = 0; i < GEMMB_GRID; i++) s += Tpart[i];
    sT = 1.0f / s;
  }
  __syncthreads();
  const int dcol = blockIdx.x * 256 + threadIdx.x;
  float s = 0.f;
  for(int b = 0; b < 256; b++) s += part[(size_t)b * DD + dcol];
  out[dcol] = s * sT;
}

// ---------- launch ----------
extern "C" void kernel_launch(void* const* d_in, const int* in_sizes, int n_in,
                              void* d_out, int out_size, void* d_ws, size_t ws_size,
                              hipStream_t stream)
{
  const float* s_prev = (const float*)d_in[0];
  const float* enc    = (const float*)d_in[1];
  const float* cmr    = (const float*)d_in[2];
  const int*   mask   = (const int*)d_in[3];
  const float* W_info = (const float*)d_in[4];
  const float* W_ctx  = (const float*)d_in[5];
  const float* W_q    = (const float*)d_in[6];
  const float* b_q    = (const float*)d_in[7];
  const float* W_p1   = (const float*)d_in[8];
  const float* b_p1   = (const float*)d_in[9];
  const float* W_p2   = (const float*)d_in[10];
  const float* b_p2   = (const float*)d_in[11];
  float* out = (float*)d_out;

  char* ws = (char*)d_ws;
  unsigned short* tanhbuf = (unsigned short*)(ws);                    // 67,108,864
  unsigned short* wctxb   = (unsigned short*)(ws + 67108864);         //  8,388,608
  unsigned short* wp1ab   = (unsigned short*)(ws + 75497472);         //  1,048,576
  int*   idx    = (int*)(ws + 76546048);                              //     65,536
  int*   cpos   = (int*)(ws + 76611584);                              //     65,536
  float* attnc  = (float*)(ws + 76677120);                            //     65,536
  float* part   = (float*)(ws + 76742656);                            //  2,097,152
  float* twq    = (float*)(ws + 78839808);                            //      8,192
  float* tdh    = (float*)(ws + 78848000);                            //      8,192
  float* bias2  = (float*)(ws + 78856192);                            //      1,024
  int*   mcount = (int*)(ws + 78857216);                              //        128
  float* Tpart  = (float*)(ws + 78857344);                            //      1,088

  mega_kernel<<<1312, 256, 0, stream>>>(W_ctx, wctxb, W_p1, wp1ab,
                                        s_prev, cmr, W_q, b_q, W_info, twq, tdh);
  scan_kernel<<<1, 1024, 0, stream>>>(mask, idx, cpos, mcount);
  gemmA_kernel<<<544, 512, 0, stream>>>(enc, idx, wctxb, mcount, tanhbuf,
                                        W_p1, b_p1, twq, tdh, bias2);
  gemmB_kernel<<<GEMMB_GRID, 512, 0, stream>>>(tanhbuf, wp1ab, mcount, bias2,
                                               W_p2, b_p2, attnc, Tpart);
  normctx_kernel<<<320, 256, 0, stream>>>(attnc, cpos, idx, mcount, Tpart,
                                          enc, out, part);
  ctxr_kernel<<<8, 256, 0, stream>>>(part, Tpart, out + SS);
}

// Round 12
// 178.790 us; speedup vs baseline: 1.3948x; 1.3948x over previous
//
#include <hip/hip_runtime.h>
#include <hip/hip_bf16.h>
#include <stdint.h>

#define DD 2048
#define SS 16384
#define HH 250
#define GEMMB_GRID 264

typedef __attribute__((ext_vector_type(8))) short bf16x8;
typedef __attribute__((ext_vector_type(4))) short bf16x4;
typedef __attribute__((ext_vector_type(4))) float f32x4;

__device__ __forceinline__ unsigned short f2bf(float f){
  union { float f; uint32_t u; } v; v.f = f;
  uint32_t u = v.u;
  return (unsigned short)((u + 0x7fffu + ((u >> 16) & 1u)) >> 16);
}
__device__ __forceinline__ float bf2f(unsigned short h){
  union { uint32_t u; float f; } v; v.u = ((uint32_t)h) << 16; return v.f;
}
__device__ __forceinline__ bf16x4 pk4(float4 a){
  bf16x4 v;
  v[0]=(short)f2bf(a.x); v[1]=(short)f2bf(a.y); v[2]=(short)f2bf(a.z); v[3]=(short)f2bf(a.w);
  return v;
}
__device__ __forceinline__ float fast_tanh(float x){
  return 1.0f - 2.0f / (1.0f + __expf(2.0f * x));
}
__device__ __forceinline__ void gl_lds16(const void* g, void* l){
  __builtin_amdgcn_global_load_lds((const __attribute__((address_space(1))) void*)g,
                                   (__attribute__((address_space(3))) void*)l, 16, 0, 0);
}

// ---------- mega: W_ctx conv | W_p1a conv | matvecs | ballot scan ----------
// roles: [0,256) W_ctx | [256,288) W_p1a | [288,1312) matvec | 1312 scan
__global__ __launch_bounds__(256) void mega_kernel(
    const float* __restrict__ W_ctx, unsigned short* __restrict__ wctxb,
    const float* __restrict__ W_p1, unsigned short* __restrict__ wp1ab,
    const float* __restrict__ s_prev, const float* __restrict__ cmr,
    const float* __restrict__ Wq, const float* __restrict__ bq,
    const float* __restrict__ Winfo,
    float* __restrict__ twq, float* __restrict__ tdh,
    const int* __restrict__ mask, int* __restrict__ idx, int* __restrict__ cpos,
    int* __restrict__ mcount)
{
  const int b = blockIdx.x, t = threadIdx.x;
  if(b < 256){                                   // W_ctx: 1,048,576 float4 chunks
    const float4* in4 = (const float4*)W_ctx;
    bf16x4* out4 = (bf16x4*)wctxb;
    const int gt = b * 256 + t;                  // 65536 threads
    for(int i = gt; i < 1048576; i += 65536) out4[i] = pk4(in4[i]);
  } else if(b < 288){                            // W_p1a: 131,072 bf16x4 chunks
    bf16x4* out4 = (bf16x4*)wp1ab;
    const int gt = (b - 256) * 256 + t;          // 8192 threads
    #pragma unroll
    for(int k = 0; k < 16; k++){
      int i = gt + k * 8192;
      int row = i >> 9, col = i & 511;
      bf16x4 v;
      if(row < HH){
        v = pk4(*(const float4*)(W_p1 + (size_t)row * (3 * DD) + (col << 2)));
      } else {
        v[0] = 0; v[1] = 0; v[2] = 0; v[3] = 0;
      }
      out4[i] = v;
    }
  } else if(b < 1312){                           // twq / tdh matvecs
    int vb = b - 288;
    int wid = t >> 6, lane = t & 63;
    bool isq = vb < 512;
    int r = (isq ? vb : vb - 512) * 4 + wid;
    const float* M = (isq ? Wq : Winfo) + (size_t)r * DD;
    const float* x = isq ? s_prev : cmr;
    float s = 0.f;
    for(int i = lane; i < DD; i += 64) s += M[i] * x[i];
    #pragma unroll
    for(int o = 32; o; o >>= 1) s += __shfl_xor(s, o);
    if(lane == 0){
      if(isq) twq[r] = fast_tanh(s + bq[r]);
      else    tdh[r] = fast_tanh(s);
    }
  } else {                                       // ballot scan: 1 block, 64 rounds
    __shared__ int wsum[4];
    const int lane = t & 63, w = t >> 6;
    int running = 0;
    for(int k = 0; k < 64; k++){
      const int e = k * 256 + t;
      const int m = (mask[e] == 0);
      unsigned long long bal = __ballot(m);
      if(lane == 0) wsum[w] = __popcll(bal);
      __syncthreads();
      int wpre = 0;
      #pragma unroll
      for(int i = 0; i < 4; i++) if(i < w) wpre += wsum[i];
      int tot = wsum[0] + wsum[1] + wsum[2] + wsum[3];
      const int lpre = __popcll(bal & ((1ull << lane) - 1ull));
      const int pos = running + wpre + lpre;
      if(m){ idx[pos] = e; cpos[e] = pos; } else cpos[e] = -1;
      running += tot;
      __syncthreads();
    }
    if(t == 0){
      mcount[0] = running;
      mcount[1] = (running + 255) & ~255;   // gemmA 256-row tile pad
      mcount[2] = (running + 63) & ~63;     // gemmB 64-row tile pad
    }
  }
}

// ---------- conv_enc (compacted f32->bf16 gather) + bias2 tail (R7 verbatim) ----------
__global__ __launch_bounds__(256) void conv_enc_kernel(
    const float* __restrict__ enc, const int* __restrict__ idx,
    const int* __restrict__ mcount, unsigned short* __restrict__ out,
    const float* __restrict__ wp1, const float* __restrict__ bp1,
    const float* __restrict__ twq, const float* __restrict__ tdh,
    float* __restrict__ bias2)
{
  const int b = blockIdx.x, t = threadIdx.x;
  if(b < 2048){
    const int mc0 = mcount[0], mc1 = mcount[1];
    #pragma unroll
    for(int r = 0; r < 8; r++){
      int j = b * 8 + r;
      if(j >= mc1) return;
      unsigned short* o = out + (size_t)j * DD + t * 8;
      if(j >= mc0){
        bf16x8 z;
        #pragma unroll
        for(int i = 0; i < 8; i++) z[i] = 0;
        *(bf16x8*)o = z;
      } else {
        const float4* p = (const float4*)(enc + (size_t)idx[j] * DD + t * 8);
        float4 a = p[0], c = p[1];
        bf16x8 v;
        v[0]=(short)f2bf(a.x); v[1]=(short)f2bf(a.y); v[2]=(short)f2bf(a.z); v[3]=(short)f2bf(a.w);
        v[4]=(short)f2bf(c.x); v[5]=(short)f2bf(c.y); v[6]=(short)f2bf(c.z); v[7]=(short)f2bf(c.w);
        *(bf16x8*)o = v;
      }
    }
  } else {                                       // bias2: 64 blocks x 4 waves
    int h = (b - 2048) * 4 + (t >> 6);
    int lane = t & 63;
    if(h >= HH){ if(lane == 0 && h < 256) bias2[h] = 0.f; return; }
    const float* r1 = wp1 + (size_t)h * (3 * DD) + DD;
    const float* r2 = wp1 + (size_t)h * (3 * DD) + 2 * DD;
    float s = 0.f;
    for(int i = lane; i < DD; i += 64) s += r1[i] * twq[i] + r2[i] * tdh[i];
    #pragma unroll
    for(int o = 32; o; o >>= 1) s += __shfl_xor(s, o);
    if(lane == 0) bias2[h] = s + bp1[h];
  }
}

// ---------- gemmA staging helper (linear LDS dest + pre-swizzled source) ----------
__device__ __forceinline__ void stage_half(const unsigned short* __restrict__ g,
                                           int grow0, int kt, char* ldsbase,
                                           int wid, int lane)
{
  const int srow = lane >> 3;
  const int c = (lane & 7) ^ srow;
  #pragma unroll
  for(int i = 0; i < 2; i++){
    int r8 = (wid * 2 + i) * 8;
    gl_lds16(g + (size_t)(grow0 + r8 + srow) * DD + kt + c * 8,
             ldsbase + r8 * 128);
  }
}
#define RDF(base, lr, kc) (*(const bf16x8*)((base) + (lr) * 128 + (((kc) * 16) ^ (((lr) & 7) << 4))))

// ---------- gemmA: tanh(encb @ W_ctx^T), BM=BN=256 BK=64, 4-phase, XCD-grouped (R7) ----------
__global__ __launch_bounds__(512, 2) void gemmA_kernel(
    const unsigned short* __restrict__ A, const unsigned short* __restrict__ B,
    const int* __restrict__ mcount, unsigned short* __restrict__ Ct)
{
  __shared__ alignas(128) char lds[131072];   // 2 bufs x (A 32KB + B 32KB)
  const int tid = threadIdx.x, lane = tid & 63, wid = tid >> 6;
  const int wm = wid >> 2, wn = wid & 3;          // 2M x 4N waves
  // XCD grouping: all 8 n-siblings of m-tile mt land on one XCD (bid%8 const)
  const int slot = blockIdx.x >> 3;
  const int mt = (blockIdx.x & 7) + ((slot >> 3) << 3);
  const int n0 = (slot & 7) * 256;
  const int MT = mcount[1] >> 8;
  if(mt >= MT) return;
  const int m0 = mt * 256;
  const int frow = lane & 15, kch = lane >> 4;

  f32x4 acc[8][4] = {};

  // prologue: tile0 (A h0,h1,B h0,h1) + tile1 B h0,h1 ; wait tile0 (8 loads)
  stage_half(A, m0,        0, lds,                 wid, lane);
  stage_half(A, m0 + 128,  0, lds + 16384,         wid, lane);
  stage_half(B, n0,        0, lds + 32768,         wid, lane);
  stage_half(B, n0 + 128,  0, lds + 49152,         wid, lane);
  stage_half(B, n0,       64, lds + 65536 + 32768, wid, lane);
  stage_half(B, n0 + 128, 64, lds + 65536 + 49152, wid, lane);
  asm volatile("s_waitcnt vmcnt(4)" ::: "memory");
  __builtin_amdgcn_s_barrier();

  #pragma unroll 2
  for(int t = 0; t < 32; t++){
    const int d = t & 1;
    char* Ab = lds + d * 65536;
    char* Bb = Ab + 32768;
    char* An = lds + (d ^ 1) * 65536;
    bf16x8 bfr[4][2];
    #pragma unroll
    for(int q = 0; q < 4; q++){
      if(q == 0){
        #pragma unroll
        for(int nr = 0; nr < 4; nr++){
          int row = wn * 64 + nr * 16 + frow;
          #pragma unroll
          for(int ks = 0; ks < 2; ks++) bfr[nr][ks] = RDF(Bb, row, ks * 4 + kch);
        }
      }
      bf16x8 afr[2][2];
      #pragma unroll
      for(int mi = 0; mi < 2; mi++){
        int row = wm * 128 + (q * 2 + mi) * 16 + frow;
        #pragma unroll
        for(int ks = 0; ks < 2; ks++) afr[mi][ks] = RDF(Ab, row, ks * 4 + kch);
      }
      if(q == 0){
        if(t + 1 < 32){
          stage_half(A, m0,       (t + 1) * 64, An,         wid, lane);
          stage_half(A, m0 + 128, (t + 1) * 64, An + 16384, wid, lane);
        }
      } else if(q == 1){
        if(t + 2 < 32) stage_half(B, n0,       (t + 2) * 64, Bb,         wid, lane);
      } else if(q == 2){
        if(t + 2 < 32) stage_half(B, n0 + 128, (t + 2) * 64, Bb + 16384, wid, lane);
      }
      __builtin_amdgcn_s_barrier();
      __builtin_amdgcn_sched_barrier(0);
      __builtin_amdgcn_s_setprio(1);
      #pragma unroll
      for(int mi = 0; mi < 2; mi++)
        #pragma unroll
        for(int nr = 0; nr < 4; nr++)
          #pragma unroll
          for(int ks = 0; ks < 2; ks++)
            acc[q * 2 + mi][nr] = __builtin_amdgcn_mfma_f32_16x16x32_bf16(
                afr[mi][ks], bfr[nr][ks], acc[q * 2 + mi][nr], 0, 0, 0);
      __builtin_amdgcn_s_setprio(0);
      __builtin_amdgcn_sched_barrier(0);
      if(q == 3){
        // steady outstanding: [B(t+1):4][A(t+1):4][B(t+2):4] -> retire first 8
        if(t < 30)       asm volatile("s_waitcnt vmcnt(4)" ::: "memory");
        else if(t == 30) asm volatile("s_waitcnt vmcnt(0)" ::: "memory");
      }
      __builtin_amdgcn_s_barrier();
    }
  }

  // epilogue: fused tanh + bf16 store (r innermost -- R3-verified clean WRITE)
  const int r0 = m0 + wm * 128 + (lane >> 4) * 4;
  const int c0 = n0 + wn * 64 + frow;
  #pragma unroll
  for(int mr = 0; mr < 8; mr++)
    #pragma unroll
    for(int nr = 0; nr < 4; nr++)
      #pragma unroll
      for(int r = 0; r < 4; r++)
        Ct[(size_t)(r0 + mr * 16 + r) * DD + c0 + nr * 16] = f2bf(fast_tanh(acc[mr][nr][r]));
}

// ---------- gemmB: e = exp(W_p2 . relu(tanh @ W_p1a^T + bias2) + b_p2) ----------
__global__ __launch_bounds__(512, 4) void gemmB_kernel(
    const unsigned short* __restrict__ A, const unsigned short* __restrict__ B,
    const int* __restrict__ mcount, const float* __restrict__ bias2,
    const float* __restrict__ w2, const float* __restrict__ bp2,
    float* __restrict__ attnc, float* __restrict__ Tpart)
{
  __shared__ alignas(128) char lds[81920];    // A 8K x2 | B 32K x2
  __shared__ float sred[8][32];
  const int tid = threadIdx.x, lane = tid & 63, wid = tid >> 6;
  const int wm = wid >> 2, wn = wid & 3;
  const int m0 = blockIdx.x * 64;
  const int mc0 = mcount[0], mc2 = mcount[2];
  if(m0 >= mc2){ if(tid == 0) Tpart[blockIdx.x] = 0.f; return; }
  const int frow = lane & 15, kch = lane >> 4;
  const int srow = lane >> 3, sc = ((lane & 7) ^ srow) * 8;

  f32x4 acc[2][4] = {};

  gl_lds16(A + (size_t)(m0 + wid * 8 + srow) * DD + sc, lds + wid * 1024);
  #pragma unroll
  for(int i = 0; i < 4; i++){
    int l = wid + 8 * i;
    gl_lds16(B + (size_t)(l * 8 + srow) * DD + sc,      lds + 16384 + l * 1024);
    gl_lds16(B + (size_t)(l * 8 + srow) * DD + 64 + sc, lds + 49152 + l * 1024);
  }
  asm volatile("s_waitcnt vmcnt(4)" ::: "memory");
  __builtin_amdgcn_s_barrier();

  #pragma unroll 2
  for(int t = 0; t < 32; t++){
    const int d = t & 1;
    char* Ab = lds + d * 8192;
    char* An = lds + (d ^ 1) * 8192;
    char* Bb = lds + 16384 + d * 32768;
    bf16x8 bfr[4][2], afr[2];
    #pragma unroll
    for(int q = 0; q < 2; q++){
      if(q == 0){
        #pragma unroll
        for(int nr = 0; nr < 4; nr++){
          int row = wn * 64 + nr * 16 + frow;
          #pragma unroll
          for(int ks = 0; ks < 2; ks++) bfr[nr][ks] = RDF(Bb, row, ks * 4 + kch);
        }
      }
      {
        int row = wm * 32 + q * 16 + frow;
        #pragma unroll
        for(int ks = 0; ks < 2; ks++) afr[ks] = RDF(Ab, row, ks * 4 + kch);
      }
      if(q == 0){
        if(t + 1 < 32)
          gl_lds16(A + (size_t)(m0 + wid * 8 + srow) * DD + (t + 1) * 64 + sc, An + wid * 1024);
      } else {
        if(t + 2 < 32){
          #pragma unroll
          for(int i = 0; i < 4; i++){
            int l = wid + 8 * i;
            gl_lds16(B + (size_t)(l * 8 + srow) * DD + (t + 2) * 64 + sc, Bb + l * 1024);
          }
        }
      }
      __builtin_amdgcn_s_barrier();
      __builtin_amdgcn_sched_barrier(0);
      __builtin_amdgcn_s_setprio(1);
      #pragma unroll
      for(int nr = 0; nr < 4; nr++)
        #pragma unroll
        for(int ks = 0; ks < 2; ks++)
          acc[q][nr] = __builtin_amdgcn_mfma_f32_16x16x32_bf16(afr[ks], bfr[nr][ks], acc[q][nr], 0, 0, 0);
      __builtin_amdgcn_s_setprio(0);
      __builtin_amdgcn_sched_barrier(0);
      if(q == 1){
        if(t < 30)       asm volatile("s_waitcnt vmcnt(4)" ::: "memory");
        else if(t == 30) asm volatile("s_waitcnt vmcnt(0)" ::: "memory");
      }
      __builtin_amdgcn_s_barrier();
    }
  }

  float w2v[4], b2v[4];
  #pragma unroll
  for(int in = 0; in < 4; in++){
    int n = wn * 64 + in * 16 + frow;
    w2v[in] = (n < HH) ? w2[n] : 0.f;
    b2v[in] = bias2[n];
  }
  #pragma unroll
  for(int mi = 0; mi < 2; mi++){
    #pragma unroll
    for(int r = 0; r < 4; r++){
      float s = 0.f;
      #pragma unroll
      for(int in = 0; in < 4; in++){
        float h = acc[mi][in][r] + b2v[in];
        s += (h > 0.f ? h : 0.f) * w2v[in];
      }
      s += __shfl_xor(s, 1); s += __shfl_xor(s, 2);
      s += __shfl_xor(s, 4); s += __shfl_xor(s, 8);
      if(frow == 0) sred[wid][mi * 16 + (lane >> 4) * 4 + r] = s;
    }
  }
  __syncthreads();
  if(tid < 64){
    int wmr = tid >> 5, rr = tid & 31;
    float s = sred[wmr * 4][rr] + sred[wmr * 4 + 1][rr] + sred[wmr * 4 + 2][rr]
            + sred[wmr * 4 + 3][rr] + bp2[0];
    int j = m0 + tid;
    float e = (j < mc0) ? __expf(s) : 0.f;
    if(j < mc0) attnc[j] = e;
    #pragma unroll
    for(int o = 32; o; o >>= 1) e += __shfl_xor(e, o);
    if(tid == 0) Tpart[blockIdx.x] = e;
  }
}

// ---------- norm+scatter (blocks 0..63) | ctx partials over encb (64..319) ----------
__global__ __launch_bounds__(256) void normctx_kernel(
    const float* __restrict__ attnc, const int* __restrict__ cpos,
    const int* __restrict__ mcount, const float* __restrict__ Tpart,
    const unsigned short* __restrict__ encb,
    float* __restrict__ out, float* __restrict__ part)
{
  const int b = blockIdx.x, t = threadIdx.x;
  if(b < 64){
    __shared__ float sT;
    if(t == 0){
      float s = 0.f;
      for(int i = 0; i < GEMMB_GRID; i++) s += Tpart[i];
      sT = 1.0f / s;
    }
    __syncthreads();
    int i = b * 256 + t;
    int cp = cpos[i];
    out[i] = (cp >= 0) ? attnc[cp] * sT : 0.f;
  } else {
    const int bb = b - 64;
    const int mc0 = mcount[0];
    const int chunk = (mc0 + 255) >> 8;
    const int j0 = bb * chunk;
    const int j1 = min(j0 + chunk, mc0);
    float a[8] = {};
    for(int j = j0; j < j1; j++){
      float e = attnc[j];
      bf16x8 v = *(const bf16x8*)(encb + (size_t)j * DD + t * 8);
      #pragma unroll
      for(int k = 0; k < 8; k++) a[k] += e * bf2f((unsigned short)v[k]);
    }
    float* o = part + (size_t)bb * DD + t * 8;
    #pragma unroll
    for(int k = 0; k < 8; k++) o[k] = a[k];
  }
}

__global__ __launch_bounds__(256) void ctxr_kernel(
    const float* __restrict__ part, const float* __restrict__ Tpart,
    float* __restrict__ out)
{
  __shared__ float sT;
  if(threadIdx.x == 0){
    float s = 0.f;
    for(int i = 0; i < GEMMB_GRID; i++) s += Tpart[i];
    sT = 1.0f / s;
  }
  __syncthreads();
  const int dcol = blockIdx.x * 256 + threadIdx.x;
  float s = 0.f;
  for(int b = 0; b < 256; b++) s += part[(size_t)b * DD + dcol];
  out[dcol] = s * sT;
}

// ---------- launch ----------
extern "C" void kernel_launch(void* const* d_in, const int* in_sizes, int n_in,
                              void* d_out, int out_size, void* d_ws, size_t ws_size,
                              hipStream_t stream)
{
  const float* s_prev = (const float*)d_in[0];
  const float* enc    = (const float*)d_in[1];
  const float* cmr    = (const float*)d_in[2];
  const int*   mask   = (const int*)d_in[3];
  const float* W_info = (const float*)d_in[4];
  const float* W_ctx  = (const float*)d_in[5];
  const float* W_q    = (const float*)d_in[6];
  const float* b_q    = (const float*)d_in[7];
  const float* W_p1   = (const float*)d_in[8];
  const float* b_p1   = (const float*)d_in[9];
  const float* W_p2   = (const float*)d_in[10];
  const float* b_p2   = (const float*)d_in[11];
  float* out = (float*)d_out;

  char* ws = (char*)d_ws;
  unsigned short* encb    = (unsigned short*)(ws);                    // 67,108,864
  unsigned short* tanhbuf = (unsigned short*)(ws + 67108864);         // 67,108,864
  unsigned short* wctxb   = (unsigned short*)(ws + 134217728);        //  8,388,608
  unsigned short* wp1ab   = (unsigned short*)(ws + 142606336);        //  1,048,576
  int*   idx    = (int*)(ws + 143654912);                             //     65,536
  int*   cpos   = (int*)(ws + 143720448);                             //     65,536
  float* attnc  = (float*)(ws + 143785984);                           //     65,536
  float* part   = (float*)(ws + 143851520);                           //  2,097,152
  float* twq    = (float*)(ws + 145948672);                           //      8,192
  float* tdh    = (float*)(ws + 145956864);                           //      8,192
  float* bias2  = (float*)(ws + 145965056);                           //      1,024
  int*   mcount = (int*)(ws + 145966080);                             //        128
  float* Tpart  = (float*)(ws + 145966208);                           //      1,088

  mega_kernel<<<1313, 256, 0, stream>>>(W_ctx, wctxb, W_p1, wp1ab,
                                        s_prev, cmr, W_q, b_q, W_info,
                                        twq, tdh, mask, idx, cpos, mcount);
  conv_enc_kernel<<<2112, 256, 0, stream>>>(enc, idx, mcount, encb,
                                            W_p1, b_p1, twq, tdh, bias2);
  gemmA_kernel<<<512, 512, 0, stream>>>(encb, wctxb, mcount, tanhbuf);
  gemmB_kernel<<<GEMMB_GRID, 512, 0, stream>>>(tanhbuf, wp1ab, mcount, bias2,
                                               W_p2, b_p2, attnc, Tpart);
  normctx_kernel<<<320, 256, 0, stream>>>(attnc, cpos, mcount, Tpart,
                                          encb, out, part);
  ctxr_kernel<<<8, 256, 0, stream>>>(part, Tpart, out + SS);
}

// Round 13
// 178.731 us; speedup vs baseline: 1.3952x; 1.0003x over previous
//
#include <hip/hip_runtime.h>
#include <hip/hip_bf16.h>
#include <stdint.h>

#define DD 2048
#define SS 16384
#define HH 250
#define GEMMB_GRID 264

typedef __attribute__((ext_vector_type(8))) short bf16x8;
typedef __attribute__((ext_vector_type(4))) short bf16x4;
typedef __attribute__((ext_vector_type(4))) float f32x4;

__device__ __forceinline__ unsigned short f2bf(float f){
  union { float f; uint32_t u; } v; v.f = f;
  uint32_t u = v.u;
  return (unsigned short)((u + 0x7fffu + ((u >> 16) & 1u)) >> 16);
}
__device__ __forceinline__ float bf2f(unsigned short h){
  union { uint32_t u; float f; } v; v.u = ((uint32_t)h) << 16; return v.f;
}
__device__ __forceinline__ bf16x4 pk4(float4 a){
  bf16x4 v;
  v[0]=(short)f2bf(a.x); v[1]=(short)f2bf(a.y); v[2]=(short)f2bf(a.z); v[3]=(short)f2bf(a.w);
  return v;
}
__device__ __forceinline__ float fast_tanh(float x){
  return 1.0f - 2.0f / (1.0f + __expf(2.0f * x));
}
__device__ __forceinline__ void gl_lds16(const void* g, void* l){
  __builtin_amdgcn_global_load_lds((const __attribute__((address_space(1))) void*)g,
                                   (__attribute__((address_space(3))) void*)l, 16, 0, 0);
}

// ---------- prep: matvecs (1024 blocks) | ballot scan (1 block) ----------
__global__ __launch_bounds__(256) void prep_kernel(
    const float* __restrict__ s_prev, const float* __restrict__ cmr,
    const float* __restrict__ Wq, const float* __restrict__ bq,
    const float* __restrict__ Winfo,
    float* __restrict__ twq, float* __restrict__ tdh,
    const int* __restrict__ mask, int* __restrict__ idx, int* __restrict__ cpos,
    int* __restrict__ mcount)
{
  const int b = blockIdx.x, t = threadIdx.x;
  if(b < 1024){                                  // twq / tdh matvecs
    int wid = t >> 6, lane = t & 63;
    bool isq = b < 512;
    int r = (isq ? b : b - 512) * 4 + wid;
    const float* M = (isq ? Wq : Winfo) + (size_t)r * DD;
    const float* x = isq ? s_prev : cmr;
    float s = 0.f;
    for(int i = lane; i < DD; i += 64) s += M[i] * x[i];
    #pragma unroll
    for(int o = 32; o; o >>= 1) s += __shfl_xor(s, o);
    if(lane == 0){
      if(isq) twq[r] = fast_tanh(s + bq[r]);
      else    tdh[r] = fast_tanh(s);
    }
  } else {                                       // ballot scan: 64 rounds
    __shared__ int wsum[4];
    const int lane = t & 63, w = t >> 6;
    int running = 0;
    for(int k = 0; k < 64; k++){
      const int e = k * 256 + t;
      const int m = (mask[e] == 0);
      unsigned long long bal = __ballot(m);
      if(lane == 0) wsum[w] = __popcll(bal);
      __syncthreads();
      int wpre = 0;
      #pragma unroll
      for(int i = 0; i < 4; i++) if(i < w) wpre += wsum[i];
      int tot = wsum[0] + wsum[1] + wsum[2] + wsum[3];
      const int lpre = __popcll(bal & ((1ull << lane) - 1ull));
      const int pos = running + wpre + lpre;
      if(m){ idx[pos] = e; cpos[e] = pos; } else cpos[e] = -1;
      running += tot;
      __syncthreads();
    }
    if(t == 0){
      mcount[0] = running;
      mcount[1] = (running + 255) & ~255;   // gemmA 256-row tile pad
      mcount[2] = (running + 63) & ~63;     // gemmB 64-row tile pad
    }
  }
}

// ---------- conv: enc gather-conv | bias2 | W_ctx conv | W_p1a conv (parallel) ----------
// roles: [0,2048) enc gather | [2048,2112) bias2 | [2112,2368) W_ctx | [2368,2400) W_p1a
__global__ __launch_bounds__(256) void conv_kernel(
    const float* __restrict__ enc, const int* __restrict__ idx,
    const int* __restrict__ mcount, unsigned short* __restrict__ encb,
    const float* __restrict__ W_ctx, unsigned short* __restrict__ wctxb,
    const float* __restrict__ W_p1, unsigned short* __restrict__ wp1ab,
    const float* __restrict__ bp1,
    const float* __restrict__ twq, const float* __restrict__ tdh,
    float* __restrict__ bias2)
{
  const int b = blockIdx.x, t = threadIdx.x;
  if(b < 2048){                                  // enc gather f32->bf16 (compacted)
    const int mc0 = mcount[0], mc1 = mcount[1];
    #pragma unroll
    for(int r = 0; r < 8; r++){
      int j = b * 8 + r;
      if(j >= mc1) return;
      unsigned short* o = encb + (size_t)j * DD + t * 8;
      if(j >= mc0){
        bf16x8 z;
        #pragma unroll
        for(int i = 0; i < 8; i++) z[i] = 0;
        *(bf16x8*)o = z;
      } else {
        const float4* p = (const float4*)(enc + (size_t)idx[j] * DD + t * 8);
        float4 a = p[0], c = p[1];
        bf16x8 v;
        v[0]=(short)f2bf(a.x); v[1]=(short)f2bf(a.y); v[2]=(short)f2bf(a.z); v[3]=(short)f2bf(a.w);
        v[4]=(short)f2bf(c.x); v[5]=(short)f2bf(c.y); v[6]=(short)f2bf(c.z); v[7]=(short)f2bf(c.w);
        *(bf16x8*)o = v;
      }
    }
  } else if(b < 2112){                           // bias2: 64 blocks x 4 waves
    int h = (b - 2048) * 4 + (t >> 6);
    int lane = t & 63;
    if(h >= HH){ if(lane == 0 && h < 256) bias2[h] = 0.f; return; }
    const float* r1 = W_p1 + (size_t)h * (3 * DD) + DD;
    const float* r2 = W_p1 + (size_t)h * (3 * DD) + 2 * DD;
    float s = 0.f;
    for(int i = lane; i < DD; i += 64) s += r1[i] * twq[i] + r2[i] * tdh[i];
    #pragma unroll
    for(int o = 32; o; o >>= 1) s += __shfl_xor(s, o);
    if(lane == 0) bias2[h] = s + bp1[h];
  } else if(b < 2368){                           // W_ctx: 1,048,576 float4 chunks
    const float4* in4 = (const float4*)W_ctx;
    bf16x4* out4 = (bf16x4*)wctxb;
    const int gt = (b - 2112) * 256 + t;         // 65536 threads
    for(int i = gt; i < 1048576; i += 65536) out4[i] = pk4(in4[i]);
  } else {                                       // W_p1a: 131,072 bf16x4 chunks
    bf16x4* out4 = (bf16x4*)wp1ab;
    const int gt = (b - 2368) * 256 + t;         // 8192 threads
    #pragma unroll
    for(int k = 0; k < 16; k++){
      int i = gt + k * 8192;
      int row = i >> 9, col = i & 511;
      bf16x4 v;
      if(row < HH){
        v = pk4(*(const float4*)(W_p1 + (size_t)row * (3 * DD) + (col << 2)));
      } else {
        v[0] = 0; v[1] = 0; v[2] = 0; v[3] = 0;
      }
      out4[i] = v;
    }
  }
}

// ---------- gemmA staging helper (linear LDS dest + pre-swizzled source) ----------
__device__ __forceinline__ void stage_half(const unsigned short* __restrict__ g,
                                           int grow0, int kt, char* ldsbase,
                                           int wid, int lane)
{
  const int srow = lane >> 3;
  const int c = (lane & 7) ^ srow;
  #pragma unroll
  for(int i = 0; i < 2; i++){
    int r8 = (wid * 2 + i) * 8;
    gl_lds16(g + (size_t)(grow0 + r8 + srow) * DD + kt + c * 8,
             ldsbase + r8 * 128);
  }
}
#define RDF(base, lr, kc) (*(const bf16x8*)((base) + (lr) * 128 + (((kc) * 16) ^ (((lr) & 7) << 4))))

// ---------- gemmA: tanh(encb @ W_ctx^T), BM=BN=256 BK=64, 4-phase, XCD-grouped ----------
__global__ __launch_bounds__(512, 2) void gemmA_kernel(
    const unsigned short* __restrict__ A, const unsigned short* __restrict__ B,
    const int* __restrict__ mcount, unsigned short* __restrict__ Ct)
{
  __shared__ alignas(128) char lds[131072];   // 2 bufs x (A 32KB + B 32KB)
  const int tid = threadIdx.x, lane = tid & 63, wid = tid >> 6;
  const int wm = wid >> 2, wn = wid & 3;          // 2M x 4N waves
  // XCD grouping: all 8 n-siblings of m-tile mt land on one XCD (bid%8 const)
  const int slot = blockIdx.x >> 3;
  const int mt = (blockIdx.x & 7) + ((slot >> 3) << 3);
  const int n0 = (slot & 7) * 256;
  const int MT = mcount[1] >> 8;
  if(mt >= MT) return;
  const int m0 = mt * 256;
  const int frow = lane & 15, kch = lane >> 4;

  f32x4 acc[8][4] = {};

  // prologue: tile0 (A h0,h1,B h0,h1) + tile1 B h0,h1 ; wait tile0 (8 loads)
  stage_half(A, m0,        0, lds,                 wid, lane);
  stage_half(A, m0 + 128,  0, lds + 16384,         wid, lane);
  stage_half(B, n0,        0, lds + 32768,         wid, lane);
  stage_half(B, n0 + 128,  0, lds + 49152,         wid, lane);
  stage_half(B, n0,       64, lds + 65536 + 32768, wid, lane);
  stage_half(B, n0 + 128, 64, lds + 65536 + 49152, wid, lane);
  asm volatile("s_waitcnt vmcnt(4)" ::: "memory");
  __builtin_amdgcn_s_barrier();

  #pragma unroll 2
  for(int t = 0; t < 32; t++){
    const int d = t & 1;
    char* Ab = lds + d * 65536;
    char* Bb = Ab + 32768;
    char* An = lds + (d ^ 1) * 65536;
    bf16x8 bfr[4][2];
    #pragma unroll
    for(int q = 0; q < 4; q++){
      if(q == 0){
        #pragma unroll
        for(int nr = 0; nr < 4; nr++){
          int row = wn * 64 + nr * 16 + frow;
          #pragma unroll
          for(int ks = 0; ks < 2; ks++) bfr[nr][ks] = RDF(Bb, row, ks * 4 + kch);
        }
      }
      bf16x8 afr[2][2];
      #pragma unroll
      for(int mi = 0; mi < 2; mi++){
        int row = wm * 128 + (q * 2 + mi) * 16 + frow;
        #pragma unroll
        for(int ks = 0; ks < 2; ks++) afr[mi][ks] = RDF(Ab, row, ks * 4 + kch);
      }
      if(q == 0){
        if(t + 1 < 32){
          stage_half(A, m0,       (t + 1) * 64, An,         wid, lane);
          stage_half(A, m0 + 128, (t + 1) * 64, An + 16384, wid, lane);
        }
      } else if(q == 1){
        if(t + 2 < 32) stage_half(B, n0,       (t + 2) * 64, Bb,         wid, lane);
      } else if(q == 2){
        if(t + 2 < 32) stage_half(B, n0 + 128, (t + 2) * 64, Bb + 16384, wid, lane);
      }
      __builtin_amdgcn_s_barrier();
      __builtin_amdgcn_sched_barrier(0);
      __builtin_amdgcn_s_setprio(1);
      #pragma unroll
      for(int mi = 0; mi < 2; mi++)
        #pragma unroll
        for(int nr = 0; nr < 4; nr++)
          #pragma unroll
          for(int ks = 0; ks < 2; ks++)
            acc[q * 2 + mi][nr] = __builtin_amdgcn_mfma_f32_16x16x32_bf16(
                afr[mi][ks], bfr[nr][ks], acc[q * 2 + mi][nr], 0, 0, 0);
      __builtin_amdgcn_s_setprio(0);
      __builtin_amdgcn_sched_barrier(0);
      if(q == 3){
        // steady outstanding: [B(t+1):4][A(t+1):4][B(t+2):4] -> retire first 8
        if(t < 30)       asm volatile("s_waitcnt vmcnt(4)" ::: "memory");
        else if(t == 30) asm volatile("s_waitcnt vmcnt(0)" ::: "memory");
      }
      __builtin_amdgcn_s_barrier();
    }
  }

  // epilogue: fused tanh + bf16 store (r innermost -- R3-verified clean WRITE)
  const int r0 = m0 + wm * 128 + (lane >> 4) * 4;
  const int c0 = n0 + wn * 64 + frow;
  #pragma unroll
  for(int mr = 0; mr < 8; mr++)
    #pragma unroll
    for(int nr = 0; nr < 4; nr++)
      #pragma unroll
      for(int r = 0; r < 4; r++)
        Ct[(size_t)(r0 + mr * 16 + r) * DD + c0 + nr * 16] = f2bf(fast_tanh(acc[mr][nr][r]));
}

// ---------- gemmB: e = exp(W_p2 . relu(tanh @ W_p1a^T + bias2) + b_p2) ----------
__global__ __launch_bounds__(512, 4) void gemmB_kernel(
    const unsigned short* __restrict__ A, const unsigned short* __restrict__ B,
    const int* __restrict__ mcount, const float* __restrict__ bias2,
    const float* __restrict__ w2, const float* __restrict__ bp2,
    float* __restrict__ attnc, float* __restrict__ Tpart)
{
  __shared__ alignas(128) char lds[81920];    // A 8K x2 | B 32K x2
  __shared__ float sred[8][32];
  const int tid = threadIdx.x, lane = tid & 63, wid = tid >> 6;
  const int wm = wid >> 2, wn = wid & 3;
  const int m0 = blockIdx.x * 64;
  const int mc0 = mcount[0], mc2 = mcount[2];
  if(m0 >= mc2){ if(tid == 0) Tpart[blockIdx.x] = 0.f; return; }
  const int frow = lane & 15, kch = lane >> 4;
  const int srow = lane >> 3, sc = ((lane & 7) ^ srow) * 8;

  f32x4 acc[2][4] = {};

  gl_lds16(A + (size_t)(m0 + wid * 8 + srow) * DD + sc, lds + wid * 1024);
  #pragma unroll
  for(int i = 0; i < 4; i++){
    int l = wid + 8 * i;
    gl_lds16(B + (size_t)(l * 8 + srow) * DD + sc,      lds + 16384 + l * 1024);
    gl_lds16(B + (size_t)(l * 8 + srow) * DD + 64 + sc, lds + 49152 + l * 1024);
  }
  asm volatile("s_waitcnt vmcnt(4)" ::: "memory");
  __builtin_amdgcn_s_barrier();

  #pragma unroll 2
  for(int t = 0; t < 32; t++){
    const int d = t & 1;
    char* Ab = lds + d * 8192;
    char* An = lds + (d ^ 1) * 8192;
    char* Bb = lds + 16384 + d * 32768;
    bf16x8 bfr[4][2], afr[2];
    #pragma unroll
    for(int q = 0; q < 2; q++){
      if(q == 0){
        #pragma unroll
        for(int nr = 0; nr < 4; nr++){
          int row = wn * 64 + nr * 16 + frow;
          #pragma unroll
          for(int ks = 0; ks < 2; ks++) bfr[nr][ks] = RDF(Bb, row, ks * 4 + kch);
        }
      }
      {
        int row = wm * 32 + q * 16 + frow;
        #pragma unroll
        for(int ks = 0; ks < 2; ks++) afr[ks] = RDF(Ab, row, ks * 4 + kch);
      }
      if(q == 0){
        if(t + 1 < 32)
          gl_lds16(A + (size_t)(m0 + wid * 8 + srow) * DD + (t + 1) * 64 + sc, An + wid * 1024);
      } else {
        if(t + 2 < 32){
          #pragma unroll
          for(int i = 0; i < 4; i++){
            int l = wid + 8 * i;
            gl_lds16(B + (size_t)(l * 8 + srow) * DD + (t + 2) * 64 + sc, Bb + l * 1024);
          }
        }
      }
      __builtin_amdgcn_s_barrier();
      __builtin_amdgcn_sched_barrier(0);
      __builtin_amdgcn_s_setprio(1);
      #pragma unroll
      for(int nr = 0; nr < 4; nr++)
        #pragma unroll
        for(int ks = 0; ks < 2; ks++)
          acc[q][nr] = __builtin_amdgcn_mfma_f32_16x16x32_bf16(afr[ks], bfr[nr][ks], acc[q][nr], 0, 0, 0);
      __builtin_amdgcn_s_setprio(0);
      __builtin_amdgcn_sched_barrier(0);
      if(q == 1){
        if(t < 30)       asm volatile("s_waitcnt vmcnt(4)" ::: "memory");
        else if(t == 30) asm volatile("s_waitcnt vmcnt(0)" ::: "memory");
      }
      __builtin_amdgcn_s_barrier();
    }
  }

  float w2v[4], b2v[4];
  #pragma unroll
  for(int in = 0; in < 4; in++){
    int n = wn * 64 + in * 16 + frow;
    w2v[in] = (n < HH) ? w2[n] : 0.f;
    b2v[in] = bias2[n];
  }
  #pragma unroll
  for(int mi = 0; mi < 2; mi++){
    #pragma unroll
    for(int r = 0; r < 4; r++){
      float s = 0.f;
      #pragma unroll
      for(int in = 0; in < 4; in++){
        float h = acc[mi][in][r] + b2v[in];
        s += (h > 0.f ? h : 0.f) * w2v[in];
      }
      s += __shfl_xor(s, 1); s += __shfl_xor(s, 2);
      s += __shfl_xor(s, 4); s += __shfl_xor(s, 8);
      if(frow == 0) sred[wid][mi * 16 + (lane >> 4) * 4 + r] = s;
    }
  }
  __syncthreads();
  if(tid < 64){
    int wmr = tid >> 5, rr = tid & 31;
    float s = sred[wmr * 4][rr] + sred[wmr * 4 + 1][rr] + sred[wmr * 4 + 2][rr]
            + sred[wmr * 4 + 3][rr] + bp2[0];
    int j = m0 + tid;
    float e = (j < mc0) ? __expf(s) : 0.f;
    if(j < mc0) attnc[j] = e;
    #pragma unroll
    for(int o = 32; o; o >>= 1) e += __shfl_xor(e, o);
    if(tid == 0) Tpart[blockIdx.x] = e;
  }
}

// ---------- norm+scatter (blocks 0..63) | ctx partials over encb (64..319) ----------
__global__ __launch_bounds__(256) void normctx_kernel(
    const float* __restrict__ attnc, const int* __restrict__ cpos,
    const int* __restrict__ mcount, const float* __restrict__ Tpart,
    const unsigned short* __restrict__ encb,
    float* __restrict__ out, float* __restrict__ part)
{
  const int b = blockIdx.x, t = threadIdx.x;
  if(b < 64){
    __shared__ float sT;
    if(t == 0){
      float s = 0.f;
      for(int i = 0; i < GEMMB_GRID; i++) s += Tpart[i];
      sT = 1.0f / s;
    }
    __syncthreads();
    int i = b * 256 + t;
    int cp = cpos[i];
    out[i] = (cp >= 0) ? attnc[cp] * sT : 0.f;
  } else {
    const int bb = b - 64;
    const int mc0 = mcount[0];
    const int chunk = (mc0 + 255) >> 8;
    const int j0 = bb * chunk;
    const int j1 = min(j0 + chunk, mc0);
    float a[8] = {};
    for(int j = j0; j < j1; j++){
      float e = attnc[j];
      bf16x8 v = *(const bf16x8*)(encb + (size_t)j * DD + t * 8);
      #pragma unroll
      for(int k = 0; k < 8; k++) a[k] += e * bf2f((unsigned short)v[k]);
    }
    float* o = part + (size_t)bb * DD + t * 8;
    #pragma unroll
    for(int k = 0; k < 8; k++) o[k] = a[k];
  }
}

__global__ __launch_bounds__(256) void ctxr_kernel(
    const float* __restrict__ part, const float* __restrict__ Tpart,
    float* __restrict__ out)
{
  __shared__ float sT;
  if(threadIdx.x == 0){
    float s = 0.f;
    for(int i = 0; i < GEMMB_GRID; i++) s += Tpart[i];
    sT = 1.0f / s;
  }
  __syncthreads();
  const int dcol = blockIdx.x * 256 + threadIdx.x;
  float s = 0.f;
  for(int b = 0; b < 256; b++) s += part[(size_t)b * DD + dcol];
  out[dcol] = s * sT;
}

// ---------- launch ----------
extern "C" void kernel_launch(void* const* d_in, const int* in_sizes, int n_in,
                              void* d_out, int out_size, void* d_ws, size_t ws_size,
                              hipStream_t stream)
{
  const float* s_prev = (const float*)d_in[0];
  const float* enc    = (const float*)d_in[1];
  const float* cmr    = (const float*)d_in[2];
  const int*   mask   = (const int*)d_in[3];
  const float* W_info = (const float*)d_in[4];
  const float* W_ctx  = (const float*)d_in[5];
  const float* W_q    = (const float*)d_in[6];
  const float* b_q    = (const float*)d_in[7];
  const float* W_p1   = (const float*)d_in[8];
  const float* b_p1   = (const float*)d_in[9];
  const float* W_p2   = (const float*)d_in[10];
  const float* b_p2   = (const float*)d_in[11];
  float* out = (float*)d_out;

  char* ws = (char*)d_ws;
  unsigned short* encb    = (unsigned short*)(ws);                    // 67,108,864
  unsigned short* tanhbuf = (unsigned short*)(ws + 67108864);         // 67,108,864
  unsigned short* wctxb   = (unsigned short*)(ws + 134217728);        //  8,388,608
  unsigned short* wp1ab   = (unsigned short*)(ws + 142606336);        //  1,048,576
  int*   idx    = (int*)(ws + 143654912);                             //     65,536
  int*   cpos   = (int*)(ws + 143720448);                             //     65,536
  float* attnc  = (float*)(ws + 143785984);                           //     65,536
  float* part   = (float*)(ws + 143851520);                           //  2,097,152
  float* twq    = (float*)(ws + 145948672);                           //      8,192
  float* tdh    = (float*)(ws + 145956864);                           //      8,192
  float* bias2  = (float*)(ws + 145965056);                           //      1,024
  int*   mcount = (int*)(ws + 145966080);                             //        128
  float* Tpart  = (float*)(ws + 145966208);                           //      1,088

  prep_kernel<<<1025, 256, 0, stream>>>(s_prev, cmr, W_q, b_q, W_info,
                                        twq, tdh, mask, idx, cpos, mcount);
  conv_kernel<<<2400, 256, 0, stream>>>(enc, idx, mcount, encb,
                                        W_ctx, wctxb, W_p1, wp1ab,
                                        b_p1, twq, tdh, bias2);
  gemmA_kernel<<<512, 512, 0, stream>>>(encb, wctxb, mcount, tanhbuf);
  gemmB_kernel<<<GEMMB_GRID, 512, 0, stream>>>(tanhbuf, wp1ab, mcount, bias2,
                                               W_p2, b_p2, attnc, Tpart);
  normctx_kernel<<<320, 256, 0, stream>>>(attnc, cpos, mcount, Tpart,
                                          encb, out, part);
  ctxr_kernel<<<8, 256, 0, stream>>>(part, Tpart, out + SS);
}

// Round 14
// 176.649 us; speedup vs baseline: 1.4117x; 1.0118x over previous
//
#include <hip/hip_runtime.h>
#include <hip/hip_bf16.h>
#include <stdint.h>

#define DD 2048
#define SS 16384
#define HH 250
#define GEMMB_GRID 264

typedef __attribute__((ext_vector_type(8))) short bf16x8;
typedef __attribute__((ext_vector_type(4))) short bf16x4;
typedef __attribute__((ext_vector_type(4))) float f32x4;

__device__ __forceinline__ unsigned short f2bf(float f){
  union { float f; uint32_t u; } v; v.f = f;
  uint32_t u = v.u;
  return (unsigned short)((u + 0x7fffu + ((u >> 16) & 1u)) >> 16);
}
__device__ __forceinline__ float bf2f(unsigned short h){
  union { uint32_t u; float f; } v; v.u = ((uint32_t)h) << 16; return v.f;
}
__device__ __forceinline__ bf16x4 pk4(float4 a){
  bf16x4 v;
  v[0]=(short)f2bf(a.x); v[1]=(short)f2bf(a.y); v[2]=(short)f2bf(a.z); v[3]=(short)f2bf(a.w);
  return v;
}
__device__ __forceinline__ float fast_tanh(float x){
  return 1.0f - 2.0f / (1.0f + __expf(2.0f * x));
}
__device__ __forceinline__ void gl_lds16(const void* g, void* l){
  __builtin_amdgcn_global_load_lds((const __attribute__((address_space(1))) void*)g,
                                   (__attribute__((address_space(3))) void*)l, 16, 0, 0);
}

// ---------- prep: matvecs (1024 blocks) | ballot scan (1 block) ----------
__global__ __launch_bounds__(256) void prep_kernel(
    const float* __restrict__ s_prev, const float* __restrict__ cmr,
    const float* __restrict__ Wq, const float* __restrict__ bq,
    const float* __restrict__ Winfo,
    float* __restrict__ twq, float* __restrict__ tdh,
    const int* __restrict__ mask, int* __restrict__ idx, int* __restrict__ cpos,
    int* __restrict__ mcount)
{
  const int b = blockIdx.x, t = threadIdx.x;
  if(b < 1024){                                  // twq / tdh matvecs
    int wid = t >> 6, lane = t & 63;
    bool isq = b < 512;
    int r = (isq ? b : b - 512) * 4 + wid;
    const float* M = (isq ? Wq : Winfo) + (size_t)r * DD;
    const float* x = isq ? s_prev : cmr;
    float s = 0.f;
    for(int i = lane; i < DD; i += 64) s += M[i] * x[i];
    #pragma unroll
    for(int o = 32; o; o >>= 1) s += __shfl_xor(s, o);
    if(lane == 0){
      if(isq) twq[r] = fast_tanh(s + bq[r]);
      else    tdh[r] = fast_tanh(s);
    }
  } else {                                       // ballot scan: 64 rounds
    __shared__ int wsum[4];
    const int lane = t & 63, w = t >> 6;
    int running = 0;
    for(int k = 0; k < 64; k++){
      const int e = k * 256 + t;
      const int m = (mask[e] == 0);
      unsigned long long bal = __ballot(m);
      if(lane == 0) wsum[w] = __popcll(bal);
      __syncthreads();
      int wpre = 0;
      #pragma unroll
      for(int i = 0; i < 4; i++) if(i < w) wpre += wsum[i];
      int tot = wsum[0] + wsum[1] + wsum[2] + wsum[3];
      const int lpre = __popcll(bal & ((1ull << lane) - 1ull));
      const int pos = running + wpre + lpre;
      if(m){ idx[pos] = e; cpos[e] = pos; } else cpos[e] = -1;
      running += tot;
      __syncthreads();
    }
    if(t == 0){
      mcount[0] = running;
      mcount[1] = (running + 255) & ~255;   // gemmA 256-row tile pad
      mcount[2] = (running + 63) & ~63;     // gemmB 64-row tile pad
    }
  }
}

// ---------- conv: enc gather-conv | bias2 | W_ctx conv | W_p1a conv (parallel) ----------
__global__ __launch_bounds__(256) void conv_kernel(
    const float* __restrict__ enc, const int* __restrict__ idx,
    const int* __restrict__ mcount, unsigned short* __restrict__ encb,
    const float* __restrict__ W_ctx, unsigned short* __restrict__ wctxb,
    const float* __restrict__ W_p1, unsigned short* __restrict__ wp1ab,
    const float* __restrict__ bp1,
    const float* __restrict__ twq, const float* __restrict__ tdh,
    float* __restrict__ bias2)
{
  const int b = blockIdx.x, t = threadIdx.x;
  if(b < 2048){                                  // enc gather f32->bf16 (compacted)
    const int mc0 = mcount[0], mc1 = mcount[1];
    #pragma unroll
    for(int r = 0; r < 8; r++){
      int j = b * 8 + r;
      if(j >= mc1) return;
      unsigned short* o = encb + (size_t)j * DD + t * 8;
      if(j >= mc0){
        bf16x8 z;
        #pragma unroll
        for(int i = 0; i < 8; i++) z[i] = 0;
        *(bf16x8*)o = z;
      } else {
        const float4* p = (const float4*)(enc + (size_t)idx[j] * DD + t * 8);
        float4 a = p[0], c = p[1];
        bf16x8 v;
        v[0]=(short)f2bf(a.x); v[1]=(short)f2bf(a.y); v[2]=(short)f2bf(a.z); v[3]=(short)f2bf(a.w);
        v[4]=(short)f2bf(c.x); v[5]=(short)f2bf(c.y); v[6]=(short)f2bf(c.z); v[7]=(short)f2bf(c.w);
        *(bf16x8*)o = v;
      }
    }
  } else if(b < 2112){                           // bias2: 64 blocks x 4 waves
    int h = (b - 2048) * 4 + (t >> 6);
    int lane = t & 63;
    if(h >= HH){ if(lane == 0 && h < 256) bias2[h] = 0.f; return; }
    const float* r1 = W_p1 + (size_t)h * (3 * DD) + DD;
    const float* r2 = W_p1 + (size_t)h * (3 * DD) + 2 * DD;
    float s = 0.f;
    for(int i = lane; i < DD; i += 64) s += r1[i] * twq[i] + r2[i] * tdh[i];
    #pragma unroll
    for(int o = 32; o; o >>= 1) s += __shfl_xor(s, o);
    if(lane == 0) bias2[h] = s + bp1[h];
  } else if(b < 2368){                           // W_ctx: 1,048,576 float4 chunks
    const float4* in4 = (const float4*)W_ctx;
    bf16x4* out4 = (bf16x4*)wctxb;
    const int gt = (b - 2112) * 256 + t;         // 65536 threads
    for(int i = gt; i < 1048576; i += 65536) out4[i] = pk4(in4[i]);
  } else {                                       // W_p1a: 131,072 bf16x4 chunks
    bf16x4* out4 = (bf16x4*)wp1ab;
    const int gt = (b - 2368) * 256 + t;         // 8192 threads
    #pragma unroll
    for(int k = 0; k < 16; k++){
      int i = gt + k * 8192;
      int row = i >> 9, col = i & 511;
      bf16x4 v;
      if(row < HH){
        v = pk4(*(const float4*)(W_p1 + (size_t)row * (3 * DD) + (col << 2)));
      } else {
        v[0] = 0; v[1] = 0; v[2] = 0; v[3] = 0;
      }
      out4[i] = v;
    }
  }
}

// ---------- gemmA staging helper (linear LDS dest + pre-swizzled source) ----------
__device__ __forceinline__ void stage_half(const unsigned short* __restrict__ g,
                                           int grow0, int kt, char* ldsbase,
                                           int wid, int lane)
{
  const int srow = lane >> 3;
  const int c = (lane & 7) ^ srow;
  #pragma unroll
  for(int i = 0; i < 2; i++){
    int r8 = (wid * 2 + i) * 8;
    gl_lds16(g + (size_t)(grow0 + r8 + srow) * DD + kt + c * 8,
             ldsbase + r8 * 128);
  }
}
#define RDF(base, lr, kc) (*(const bf16x8*)((base) + (lr) * 128 + (((kc) * 16) ^ (((lr) & 7) << 4))))

// ---------- gemmA: tanh(encb @ W_ctx^T), BM=BN=256 BK=64, 4-phase, XCD-grouped
//            main class (bid<256, m-tiles 0..31) + tail class (bid 256..287, rows >= 8192) ----------
__global__ __launch_bounds__(512, 2) void gemmA_kernel(
    const unsigned short* __restrict__ A, const unsigned short* __restrict__ B,
    const int* __restrict__ mcount, unsigned short* __restrict__ Ct)
{
  __shared__ alignas(128) char lds[131072];   // 2 bufs x (A 32KB + B 32KB)
  const int tid = threadIdx.x, lane = tid & 63, wid = tid >> 6;
  const int frow = lane & 15, kch = lane >> 4;
  const int srow = lane >> 3;
  const int sc = ((lane & 7) ^ srow) * 8;

  if(blockIdx.x < 256){
    // ---------------- main class: m-tiles 0..31 (one scheduling round) -------------
    const int wm = wid >> 2, wn = wid & 3;          // 2M x 4N waves
    const int slot = blockIdx.x >> 3;
    const int mt = (blockIdx.x & 7) + ((slot >> 3) << 3);   // XCD-grouped
    const int n0 = (slot & 7) * 256;
    const int MT = mcount[1] >> 8;
    if(mt >= MT || mt >= 32) return;
    const int m0 = mt * 256;

    f32x4 acc[8][4] = {};

    stage_half(A, m0,        0, lds,                 wid, lane);
    stage_half(A, m0 + 128,  0, lds + 16384,         wid, lane);
    stage_half(B, n0,        0, lds + 32768,         wid, lane);
    stage_half(B, n0 + 128,  0, lds + 49152,         wid, lane);
    stage_half(B, n0,       64, lds + 65536 + 32768, wid, lane);
    stage_half(B, n0 + 128, 64, lds + 65536 + 49152, wid, lane);
    asm volatile("s_waitcnt vmcnt(4)" ::: "memory");
    __builtin_amdgcn_s_barrier();

    #pragma unroll 2
    for(int t = 0; t < 32; t++){
      const int d = t & 1;
      char* Ab = lds + d * 65536;
      char* Bb = Ab + 32768;
      char* An = lds + (d ^ 1) * 65536;
      bf16x8 bfr[4][2];
      #pragma unroll
      for(int q = 0; q < 4; q++){
        if(q == 0){
          #pragma unroll
          for(int nr = 0; nr < 4; nr++){
            int row = wn * 64 + nr * 16 + frow;
            #pragma unroll
            for(int ks = 0; ks < 2; ks++) bfr[nr][ks] = RDF(Bb, row, ks * 4 + kch);
          }
        }
        bf16x8 afr[2][2];
        #pragma unroll
        for(int mi = 0; mi < 2; mi++){
          int row = wm * 128 + (q * 2 + mi) * 16 + frow;
          #pragma unroll
          for(int ks = 0; ks < 2; ks++) afr[mi][ks] = RDF(Ab, row, ks * 4 + kch);
        }
        if(q == 0){
          if(t + 1 < 32){
            stage_half(A, m0,       (t + 1) * 64, An,         wid, lane);
            stage_half(A, m0 + 128, (t + 1) * 64, An + 16384, wid, lane);
          }
        } else if(q == 1){
          if(t + 2 < 32) stage_half(B, n0,       (t + 2) * 64, Bb,         wid, lane);
        } else if(q == 2){
          if(t + 2 < 32) stage_half(B, n0 + 128, (t + 2) * 64, Bb + 16384, wid, lane);
        }
        __builtin_amdgcn_s_barrier();
        __builtin_amdgcn_sched_barrier(0);
        __builtin_amdgcn_s_setprio(1);
        #pragma unroll
        for(int mi = 0; mi < 2; mi++)
          #pragma unroll
          for(int nr = 0; nr < 4; nr++)
            #pragma unroll
            for(int ks = 0; ks < 2; ks++)
              acc[q * 2 + mi][nr] = __builtin_amdgcn_mfma_f32_16x16x32_bf16(
                  afr[mi][ks], bfr[nr][ks], acc[q * 2 + mi][nr], 0, 0, 0);
        __builtin_amdgcn_s_setprio(0);
        __builtin_amdgcn_sched_barrier(0);
        if(q == 3){
          if(t < 30)       asm volatile("s_waitcnt vmcnt(4)" ::: "memory");
          else if(t == 30) asm volatile("s_waitcnt vmcnt(0)" ::: "memory");
        }
        __builtin_amdgcn_s_barrier();
      }
    }

    const int r0 = m0 + wm * 128 + (lane >> 4) * 4;
    const int c0 = n0 + wn * 64 + frow;
    #pragma unroll
    for(int mr = 0; mr < 8; mr++)
      #pragma unroll
      for(int nr = 0; nr < 4; nr++)
        #pragma unroll
        for(int r = 0; r < 4; r++)
          Ct[(size_t)(r0 + mr * 16 + r) * DD + c0 + nr * 16] = f2bf(fast_tanh(acc[mr][nr][r]));
    return;
  }

  // ---------------- tail class: rows [8192, mc1), BM=64 BN=256, gemmB-style -------
  const int mc1 = mcount[1];
  if(mc1 <= 8192) return;
  const int tb = blockIdx.x - 256;               // 0..31
  const int n0t = (tb & 7) * 256;
  const int wm = wid >> 2, wn = wid & 3;

  for(int ms = (tb >> 3); 8192 + ms * 64 < mc1; ms += 4){
    const int m0t = 8192 + ms * 64;
    f32x4 acc2[2][4] = {};

    gl_lds16(A + (size_t)(m0t + wid * 8 + srow) * DD + sc, lds + wid * 1024);
    #pragma unroll
    for(int i = 0; i < 4; i++){
      int l = wid + 8 * i;
      gl_lds16(B + (size_t)(n0t + l * 8 + srow) * DD + sc,      lds + 16384 + l * 1024);
      gl_lds16(B + (size_t)(n0t + l * 8 + srow) * DD + 64 + sc, lds + 49152 + l * 1024);
    }
    asm volatile("s_waitcnt vmcnt(4)" ::: "memory");
    __builtin_amdgcn_s_barrier();

    #pragma unroll 2
    for(int t = 0; t < 32; t++){
      const int d = t & 1;
      char* Ab = lds + d * 8192;
      char* An = lds + (d ^ 1) * 8192;
      char* Bb = lds + 16384 + d * 32768;
      bf16x8 bfr[4][2], afr[2];
      #pragma unroll
      for(int q = 0; q < 2; q++){
        if(q == 0){
          #pragma unroll
          for(int nr = 0; nr < 4; nr++){
            int row = wn * 64 + nr * 16 + frow;
            #pragma unroll
            for(int ks = 0; ks < 2; ks++) bfr[nr][ks] = RDF(Bb, row, ks * 4 + kch);
          }
        }
        {
          int row = wm * 32 + q * 16 + frow;
          #pragma unroll
          for(int ks = 0; ks < 2; ks++) afr[ks] = RDF(Ab, row, ks * 4 + kch);
        }
        if(q == 0){
          if(t + 1 < 32)
            gl_lds16(A + (size_t)(m0t + wid * 8 + srow) * DD + (t + 1) * 64 + sc, An + wid * 1024);
        } else {
          if(t + 2 < 32){
            #pragma unroll
            for(int i = 0; i < 4; i++){
              int l = wid + 8 * i;
              gl_lds16(B + (size_t)(n0t + l * 8 + srow) * DD + (t + 2) * 64 + sc, Bb + l * 1024);
            }
          }
        }
        __builtin_amdgcn_s_barrier();
        __builtin_amdgcn_sched_barrier(0);
        __builtin_amdgcn_s_setprio(1);
        #pragma unroll
        for(int nr = 0; nr < 4; nr++)
          #pragma unroll
          for(int ks = 0; ks < 2; ks++)
            acc2[q][nr] = __builtin_amdgcn_mfma_f32_16x16x32_bf16(afr[ks], bfr[nr][ks], acc2[q][nr], 0, 0, 0);
        __builtin_amdgcn_s_setprio(0);
        __builtin_amdgcn_sched_barrier(0);
        if(q == 1){
          if(t < 30)       asm volatile("s_waitcnt vmcnt(4)" ::: "memory");
          else if(t == 30) asm volatile("s_waitcnt vmcnt(0)" ::: "memory");
        }
        __builtin_amdgcn_s_barrier();
      }
    }

    const int r0t = m0t + wm * 32 + (lane >> 4) * 4;
    const int c0t = n0t + wn * 64 + frow;
    #pragma unroll
    for(int mi = 0; mi < 2; mi++)
      #pragma unroll
      for(int in = 0; in < 4; in++)
        #pragma unroll
        for(int r = 0; r < 4; r++)
          Ct[(size_t)(r0t + mi * 16 + r) * DD + c0t + in * 16] = f2bf(fast_tanh(acc2[mi][in][r]));
    __builtin_amdgcn_s_barrier();
  }
}

// ---------- gemmB: e = exp(W_p2 . relu(tanh @ W_p1a^T + bias2) + b_p2) ----------
__global__ __launch_bounds__(512, 4) void gemmB_kernel(
    const unsigned short* __restrict__ A, const unsigned short* __restrict__ B,
    const int* __restrict__ mcount, const float* __restrict__ bias2,
    const float* __restrict__ w2, const float* __restrict__ bp2,
    float* __restrict__ attnc, float* __restrict__ Tpart)
{
  __shared__ alignas(128) char lds[81920];    // A 8K x2 | B 32K x2
  __shared__ float sred[8][32];
  const int tid = threadIdx.x, lane = tid & 63, wid = tid >> 6;
  const int wm = wid >> 2, wn = wid & 3;
  const int m0 = blockIdx.x * 64;
  const int mc0 = mcount[0], mc2 = mcount[2];
  if(m0 >= mc2){ if(tid == 0) Tpart[blockIdx.x] = 0.f; return; }
  const int frow = lane & 15, kch = lane >> 4;
  const int srow = lane >> 3, sc = ((lane & 7) ^ srow) * 8;

  f32x4 acc[2][4] = {};

  gl_lds16(A + (size_t)(m0 + wid * 8 + srow) * DD + sc, lds + wid * 1024);
  #pragma unroll
  for(int i = 0; i < 4; i++){
    int l = wid + 8 * i;
    gl_lds16(B + (size_t)(l * 8 + srow) * DD + sc,      lds + 16384 + l * 1024);
    gl_lds16(B + (size_t)(l * 8 + srow) * DD + 64 + sc, lds + 49152 + l * 1024);
  }
  asm volatile("s_waitcnt vmcnt(4)" ::: "memory");
  __builtin_amdgcn_s_barrier();

  #pragma unroll 2
  for(int t = 0; t < 32; t++){
    const int d = t & 1;
    char* Ab = lds + d * 8192;
    char* An = lds + (d ^ 1) * 8192;
    char* Bb = lds + 16384 + d * 32768;
    bf16x8 bfr[4][2], afr[2];
    #pragma unroll
    for(int q = 0; q < 2; q++){
      if(q == 0){
        #pragma unroll
        for(int nr = 0; nr < 4; nr++){
          int row = wn * 64 + nr * 16 + frow;
          #pragma unroll
          for(int ks = 0; ks < 2; ks++) bfr[nr][ks] = RDF(Bb, row, ks * 4 + kch);
        }
      }
      {
        int row = wm * 32 + q * 16 + frow;
        #pragma unroll
        for(int ks = 0; ks < 2; ks++) afr[ks] = RDF(Ab, row, ks * 4 + kch);
      }
      if(q == 0){
        if(t + 1 < 32)
          gl_lds16(A + (size_t)(m0 + wid * 8 + srow) * DD + (t + 1) * 64 + sc, An + wid * 1024);
      } else {
        if(t + 2 < 32){
          #pragma unroll
          for(int i = 0; i < 4; i++){
            int l = wid + 8 * i;
            gl_lds16(B + (size_t)(l * 8 + srow) * DD + (t + 2) * 64 + sc, Bb + l * 1024);
          }
        }
      }
      __builtin_amdgcn_s_barrier();
      __builtin_amdgcn_sched_barrier(0);
      __builtin_amdgcn_s_setprio(1);
      #pragma unroll
      for(int nr = 0; nr < 4; nr++)
        #pragma unroll
        for(int ks = 0; ks < 2; ks++)
          acc[q][nr] = __builtin_amdgcn_mfma_f32_16x16x32_bf16(afr[ks], bfr[nr][ks], acc[q][nr], 0, 0, 0);
      __builtin_amdgcn_s_setprio(0);
      __builtin_amdgcn_sched_barrier(0);
      if(q == 1){
        if(t < 30)       asm volatile("s_waitcnt vmcnt(4)" ::: "memory");
        else if(t == 30) asm volatile("s_waitcnt vmcnt(0)" ::: "memory");
      }
      __builtin_amdgcn_s_barrier();
    }
  }

  float w2v[4], b2v[4];
  #pragma unroll
  for(int in = 0; in < 4; in++){
    int n = wn * 64 + in * 16 + frow;
    w2v[in] = (n < HH) ? w2[n] : 0.f;
    b2v[in] = bias2[n];
  }
  #pragma unroll
  for(int mi = 0; mi < 2; mi++){
    #pragma unroll
    for(int r = 0; r < 4; r++){
      float s = 0.f;
      #pragma unroll
      for(int in = 0; in < 4; in++){
        float h = acc[mi][in][r] + b2v[in];
        s += (h > 0.f ? h : 0.f) * w2v[in];
      }
      s += __shfl_xor(s, 1); s += __shfl_xor(s, 2);
      s += __shfl_xor(s, 4); s += __shfl_xor(s, 8);
      if(frow == 0) sred[wid][mi * 16 + (lane >> 4) * 4 + r] = s;
    }
  }
  __syncthreads();
  if(tid < 64){
    int wmr = tid >> 5, rr = tid & 31;
    float s = sred[wmr * 4][rr] + sred[wmr * 4 + 1][rr] + sred[wmr * 4 + 2][rr]
            + sred[wmr * 4 + 3][rr] + bp2[0];
    int j = m0 + tid;
    float e = (j < mc0) ? __expf(s) : 0.f;
    if(j < mc0) attnc[j] = e;
    #pragma unroll
    for(int o = 32; o; o >>= 1) e += __shfl_xor(e, o);
    if(tid == 0) Tpart[blockIdx.x] = e;
  }
}

// ---------- norm+scatter (blocks 0..63) | ctx partials over encb (64..319) ----------
__global__ __launch_bounds__(256) void normctx_kernel(
    const float* __restrict__ attnc, const int* __restrict__ cpos,
    const int* __restrict__ mcount, const float* __restrict__ Tpart,
    const unsigned short* __restrict__ encb,
    float* __restrict__ out, float* __restrict__ part)
{
  const int b = blockIdx.x, t = threadIdx.x;
  if(b < 64){
    __shared__ float sT;
    if(t == 0){
      float s = 0.f;
      for(int i = 0; i < GEMMB_GRID; i++) s += Tpart[i];
      sT = 1.0f / s;
    }
    __syncthreads();
    int i = b * 256 + t;
    int cp = cpos[i];
    out[i] = (cp >= 0) ? attnc[cp] * sT : 0.f;
  } else {
    const int bb = b - 64;
    const int mc0 = mcount[0];
    const int chunk = (mc0 + 255) >> 8;
    const int j0 = bb * chunk;
    const int j1 = min(j0 + chunk, mc0);
    float a[8] = {};
    for(int j = j0; j < j1; j++){
      float e = attnc[j];
      bf16x8 v = *(const bf16x8*)(encb + (size_t)j * DD + t * 8);
      #pragma unroll
      for(int k = 0; k < 8; k++) a[k] += e * bf2f((unsigned short)v[k]);
    }
    float* o = part + (size_t)bb * DD + t * 8;
    #pragma unroll
    for(int k = 0; k < 8; k++) o[k] = a[k];
  }
}

__global__ __launch_bounds__(256) void ctxr_kernel(
    const float* __restrict__ part, const float* __restrict__ Tpart,
    float* __restrict__ out)
{
  __shared__ float sT;
  if(threadIdx.x == 0){
    float s = 0.f;
    for(int i = 0; i < GEMMB_GRID; i++) s += Tpart[i];
    sT = 1.0f / s;
  }
  __syncthreads();
  const int dcol = blockIdx.x * 256 + threadIdx.x;
  float s = 0.f;
  for(int b = 0; b < 256; b++) s += part[(size_t)b * DD + dcol];
  out[dcol] = s * sT;
}

// ---------- launch ----------
extern "C" void kernel_launch(void* const* d_in, const int* in_sizes, int n_in,
                              void* d_out, int out_size, void* d_ws, size_t ws_size,
                              hipStream_t stream)
{
  const float* s_prev = (const float*)d_in[0];
  const float* enc    = (const float*)d_in[1];
  const float* cmr    = (const float*)d_in[2];
  const int*   mask   = (const int*)d_in[3];
  const float* W_info = (const float*)d_in[4];
  const float* W_ctx  = (const float*)d_in[5];
  const float* W_q    = (const float*)d_in[6];
  const float* b_q    = (const float*)d_in[7];
  const float* W_p1   = (const float*)d_in[8];
  const float* b_p1   = (const float*)d_in[9];
  const float* W_p2   = (const float*)d_in[10];
  const float* b_p2   = (const float*)d_in[11];
  float* out = (float*)d_out;

  char* ws = (char*)d_ws;
  unsigned short* encb    = (unsigned short*)(ws);                    // 67,108,864
  unsigned short* tanhbuf = (unsigned short*)(ws + 67108864);         // 67,108,864
  unsigned short* wctxb   = (unsigned short*)(ws + 134217728);        //  8,388,608
  unsigned short* wp1ab   = (unsigned short*)(ws + 142606336);        //  1,048,576
  int*   idx    = (int*)(ws + 143654912);                             //     65,536
  int*   cpos   = (int*)(ws + 143720448);                             //     65,536
  float* attnc  = (float*)(ws + 143785984);                           //     65,536
  float* part   = (float*)(ws + 143851520);                           //  2,097,152
  float* twq    = (float*)(ws + 145948672);                           //      8,192
  float* tdh    = (float*)(ws + 145956864);                           //      8,192
  float* bias2  = (float*)(ws + 145965056);                           //      1,024
  int*   mcount = (int*)(ws + 145966080);                             //        128
  float* Tpart  = (float*)(ws + 145966208);                           //      1,088

  prep_kernel<<<1025, 256, 0, stream>>>(s_prev, cmr, W_q, b_q, W_info,
                                        twq, tdh, mask, idx, cpos, mcount);
  conv_kernel<<<2400, 256, 0, stream>>>(enc, idx, mcount, encb,
                                        W_ctx, wctxb, W_p1, wp1ab,
                                        b_p1, twq, tdh, bias2);
  gemmA_kernel<<<288, 512, 0, stream>>>(encb, wctxb, mcount, tanhbuf);
  gemmB_kernel<<<GEMMB_GRID, 512, 0, stream>>>(tanhbuf, wp1ab, mcount, bias2,
                                               W_p2, b_p2, attnc, Tpart);
  normctx_kernel<<<320, 256, 0, stream>>>(attnc, cpos, mcount, Tpart,
                                          encb, out, part);
  ctxr_kernel<<<8, 256, 0, stream>>>(part, Tpart, out + SS);
}